// Round 6
// baseline (203.849 us; speedup 1.0000x reference)
//
#include <hip/hip_runtime.h>
#include <hip/hip_bf16.h>
#include <math.h>

#define NNODES 100000
#define NEDGES 600000
#define IN 128
#define HD 128   // NUM_HEADS * OUT_DIM
#define NH 8
#define NEG_SLOPE 0.2f
#define RG_TOTAL (NNODES / 16)   // 6250 row-groups of 16 (exact)
#define NFRAG 36                 // 4 K-steps * 9 col-tiles
#define CT_ALL 9                 // 8 z col-tiles + 1 [el|er] tile

typedef __attribute__((ext_vector_type(8))) short short8v;
typedef __attribute__((ext_vector_type(4))) float f32x4;

__device__ inline unsigned short f2bf(float f) {
    unsigned u = __float_as_uint(f);
    unsigned r = (u + 0x7fff + ((u >> 16) & 1)) >> 16;
    return (unsigned short)r;
}
__device__ inline float bflo(unsigned v) { return __uint_as_float(v << 16); }
__device__ inline float bfhi(unsigned v) { return __uint_as_float(v & 0xffff0000u); }

// ---------------- pack W (+ fused Wl/Wr logit columns) into MFMA fragment order ----------------
__global__ __launch_bounds__(256) void k_pack(
    const float* __restrict__ W, const float* __restrict__ attn_l, const float* __restrict__ attn_r,
    short8v* __restrict__ Wb)
{
    int t = threadIdx.x;
    for (int slot = t; slot < NFRAG * 64; slot += 256) {
        int f = slot >> 6, lane = slot & 63;
        int ks = f / CT_ALL, ct = f % CT_ALL;
        int k0 = ks * 32 + (lane >> 4) * 8;
        short8v v;
        if (ct < 8) {
            int col = ct * 16 + (lane & 15);
            #pragma unroll
            for (int j = 0; j < 8; ++j) v[j] = (short)f2bf(W[(k0 + j) * HD + col]);
        } else {
            int c = lane & 15;
            const float* av = (c < 8) ? attn_l : attn_r;
            int hh = c & 7;
            #pragma unroll
            for (int j = 0; j < 8; ++j) {
                int k = k0 + j;
                float s = 0.f;
                for (int d = 0; d < 16; ++d) s += W[k * HD + hh * 16 + d] * av[hh * 16 + d];
                v[j] = (short)f2bf(s);
            }
        }
        Wb[slot] = v;
    }
}

// ---------------- MFMA GEMM: z = h@W (bf16 out) + el/er ----------------
__global__ __launch_bounds__(256) void k_gemm_mfma(
    const float* __restrict__ h, const short8v* __restrict__ Wb,
    unsigned short* __restrict__ z, float* __restrict__ el, float* __restrict__ er)
{
    __shared__ short8v Bs[NFRAG * 64];   // 36 KB
    const int tid = threadIdx.x;
    {
        const float4* srcp = (const float4*)Wb;
        float4* dstp = (float4*)Bs;
        for (int i = tid; i < NFRAG * 64; i += 256) dstp[i] = srcp[i];
    }
    __syncthreads();

    const int lane  = tid & 63;
    const int rowIn = lane & 15;
    const int kgrp  = lane >> 4;
    int wid = (blockIdx.x * 256 + tid) >> 6;
    const int nw = gridDim.x * 4;

    for (int rg = wid; rg < RG_TOTAL; rg += nw) {
        const int row0 = rg * 16;
        const float* hp = h + (size_t)(row0 + rowIn) * IN + kgrp * 8;

        short8v afr[4];
        #pragma unroll
        for (int ks = 0; ks < 4; ++ks) {
            float4 a0 = *(const float4*)(hp + ks * 32);
            float4 a1 = *(const float4*)(hp + ks * 32 + 4);
            short8v v;
            v[0] = (short)f2bf(a0.x); v[1] = (short)f2bf(a0.y);
            v[2] = (short)f2bf(a0.z); v[3] = (short)f2bf(a0.w);
            v[4] = (short)f2bf(a1.x); v[5] = (short)f2bf(a1.y);
            v[6] = (short)f2bf(a1.z); v[7] = (short)f2bf(a1.w);
            afr[ks] = v;
        }

        f32x4 acc[CT_ALL];
        #pragma unroll
        for (int ct = 0; ct < CT_ALL; ++ct) acc[ct] = (f32x4){0.f, 0.f, 0.f, 0.f};

        #pragma unroll
        for (int ks = 0; ks < 4; ++ks)
            #pragma unroll
            for (int ct = 0; ct < CT_ALL; ++ct)
                acc[ct] = __builtin_amdgcn_mfma_f32_16x16x32_bf16(
                    afr[ks], Bs[(ks * CT_ALL + ct) * 64 + lane], acc[ct], 0, 0, 0);

        const int rbase = row0 + kgrp * 4;
        #pragma unroll
        for (int ct = 0; ct < 8; ++ct)
            #pragma unroll
            for (int r = 0; r < 4; ++r)
                z[(size_t)(rbase + r) * HD + ct * 16 + rowIn] = f2bf(acc[ct][r]);

        #pragma unroll
        for (int r = 0; r < 4; ++r) {
            float v = acc[8][r];
            int row = rbase + r;
            if (rowIn < 8) el[row * NH + rowIn] = v;
            else           er[row * NH + rowIn - 8] = v;
        }
    }
}

// ---------------- ex = exp(lrelu(el[dst[e]]+er[src[e]])), indexed by ORIGINAL edge id ----------------
// depends only on inputs + el/er -> content is identical on every call
__global__ __launch_bounds__(256) void k_ex(
    const int* __restrict__ src, const int* __restrict__ dst,
    const float* __restrict__ el, const float* __restrict__ er,
    float* __restrict__ exbuf)
{
    int t = blockIdx.x * blockDim.x + threadIdx.x;
    if (t >= NEDGES * NH) return;
    int e = t >> 3, hh = t & 7;
    int s = src[e], d = dst[e];
    float ev = el[d * NH + hh] + er[s * NH + hh];
    ev = (ev >= 0.f) ? ev : NEG_SLOPE * ev;
    exbuf[t] = __expf(ev);
}

// ---------------- CSR build ----------------
__global__ void k_hist(const int* __restrict__ dst, int* __restrict__ cnt) {
    int e = blockIdx.x * blockDim.x + threadIdx.x;
    if (e >= NEDGES) return;
    atomicAdd(&cnt[dst[e]], 1);
}

__global__ __launch_bounds__(1024) void kscan1(const int* __restrict__ cnt,
                                               int* __restrict__ inc, int* __restrict__ bsum) {
    __shared__ int buf[2][1024];
    int t = threadIdx.x;
    int i = blockIdx.x * 1024 + t;
    int v = (i < NNODES) ? cnt[i] : 0;
    buf[0][t] = v; __syncthreads();
    int cur = 0;
    for (int off = 1; off < 1024; off <<= 1) {
        int nv = buf[cur][t];
        if (t >= off) nv += buf[cur][t - off];
        buf[cur ^ 1][t] = nv; __syncthreads();
        cur ^= 1;
    }
    if (i < NNODES) inc[i] = buf[cur][t];
    if (t == 1023) bsum[blockIdx.x] = buf[cur][1023];
}

__global__ __launch_bounds__(128) void kscan2(int* __restrict__ bsum, int n) {
    __shared__ int buf[2][128];
    int t = threadIdx.x;
    int v = (t < n) ? bsum[t] : 0;
    buf[0][t] = v; __syncthreads();
    int cur = 0;
    for (int off = 1; off < 128; off <<= 1) {
        int nv = buf[cur][t];
        if (t >= off) nv += buf[cur][t - off];
        buf[cur ^ 1][t] = nv; __syncthreads();
        cur ^= 1;
    }
    if (t < n) bsum[t] = buf[cur][t] - v;
}

__global__ __launch_bounds__(1024) void kscan3(const int* __restrict__ cnt, const int* __restrict__ inc,
                                               const int* __restrict__ bsum,
                                               int* __restrict__ offs, int* __restrict__ cursor) {
    int t = threadIdx.x;
    int i = blockIdx.x * 1024 + t;
    if (i < NNODES) {
        int ex = inc[i] - cnt[i] + bsum[blockIdx.x];
        offs[i] = ex;
        cursor[i] = ex;
    }
    if (i == 0) offs[NNODES] = NEDGES;
}

// scatter {src[e], e} together: k_agg's two gather keys come from one 8B load
__global__ void k_scatter(const int* __restrict__ src, const int* __restrict__ dst,
                          int* __restrict__ cursor, int2* __restrict__ epair) {
    int e = blockIdx.x * blockDim.x + threadIdx.x;
    if (e >= NEDGES) return;
    int d = dst[e];
    int pos = atomicAdd(&cursor[d], 1);
    epair[pos] = make_int2(src[e], e);
}

// ---------------- aggregate: TWO waves per destination node, LDS combine ----------------
// block = 256 thr = 4 waves = 2 nodes; lane l covers columns 2l,2l+1; hh = l>>3
__global__ __launch_bounds__(256) void k_agg(
    const int* __restrict__ offs, const int2* __restrict__ epair,
    const float* __restrict__ exbuf,
    const unsigned short* __restrict__ z, const float* __restrict__ o,
    float* __restrict__ out)
{
    __shared__ float4 part[256];
    const int tid  = threadIdx.x;
    const int wv   = tid >> 6;            // 0..3
    const int lane = tid & 63;
    const int node = blockIdx.x * 2 + (wv >> 1);   // NNODES even, grid exact
    const int half = wv & 1;
    const int hh   = lane >> 3;

    const int p0n = offs[node];
    const int n_all = offs[node + 1] - p0n;
    const int nh0 = (n_all + 1) >> 1;
    const int pa = p0n + (half ? nh0 : 0);
    const int n  = half ? (n_all - nh0) : nh0;

    float srun = 0.f, a0 = 0.f, a1 = 0.f;

    if (n > 0) {
        int2 se = epair[pa];
        float ex = exbuf[se.y * NH + hh];
        unsigned zb = ((const unsigned*)(z + (size_t)se.x * HD))[lane];
        int2 se_n = (n > 1) ? epair[pa + 1] : make_int2(0, 0);

        for (int i = 0; i < n; ++i) {
            int2 se_nn = (i + 2 < n) ? epair[pa + i + 2] : make_int2(0, 0);
            float ex_n = 0.f; unsigned zb_n = 0;
            if (i + 1 < n) {
                ex_n = exbuf[se_n.y * NH + hh];
                zb_n = ((const unsigned*)(z + (size_t)se_n.x * HD))[lane];
            }
            srun += ex;
            a0 = fmaf(ex, bflo(zb), a0);
            a1 = fmaf(ex, bfhi(zb), a1);
            ex = ex_n; zb = zb_n; se_n = se_nn;
        }
    }

    part[tid] = make_float4(srun, a0, a1, 0.f);
    __syncthreads();

    if (half == 0) {
        float4 q = part[tid + 64];
        srun += q.x; a0 += q.y; a1 += q.z;

        const size_t base = (size_t)node * HD + 2 * lane;
        float inv = (srun > 0.f) ? 1.f / srun : 0.f;
        float r0 = a0 * inv, r1 = a1 * inv;
        r0 = (r0 > 0.f) ? r0 : expm1f(r0);
        r1 = (r1 > 0.f) ? r1 : expm1f(r1);
        out[base]     = o[base]     + r0;
        out[base + 1] = o[base + 1] + r1;
    }
}

extern "C" void kernel_launch(void* const* d_in, const int* in_sizes, int n_in,
                              void* d_out, int out_size, void* d_ws, size_t ws_size,
                              hipStream_t stream) {
    const float* h      = (const float*)d_in[0];
    const float* o      = (const float*)d_in[1];
    const float* W      = (const float*)d_in[2];
    const float* attn_l = (const float*)d_in[3];
    const float* attn_r = (const float*)d_in[4];
    const int*   src    = (const int*)d_in[5];
    const int*   dst    = (const int*)d_in[6];
    float* out = (float*)d_out;

    char* ws = (char*)d_ws;
    unsigned short* z = (unsigned short*)(ws);         // 25,600,000 B (bf16)
    float* el     = (float*)(ws + 25600000);           //  3,200,000
    float* er     = (float*)(ws + 28800000);           //  3,200,000
    int*   cnt    = (int*)  (ws + 32000000);           //    400,000
    int*   inc    = (int*)  (ws + 32400000);           //    400,000
    int*   offs   = (int*)  (ws + 32800000);           //    400,016
    int*   cursor = (int*)  (ws + 33200016);           //    400,000
    int*   bsum   = (int*)  (ws + 33600016);           //        512
    int2*  epair  = (int2*) (ws + 33600528);           //  4,800,000 (8B aligned)
    float* exbuf  = (float*)(ws + 38400528);           // 19,200,000
    short8v* Wb   = (short8v*)(ws + 57600528);         //     36,864  (end ~57.6 MB)

    const int SCAN_BLOCKS = (NNODES + 1023) / 1024;    // 98

    hipMemsetAsync(cnt, 0, NNODES * sizeof(int), stream);

    k_pack<<<1, 256, 0, stream>>>(W, attn_l, attn_r, Wb);
    k_gemm_mfma<<<512, 256, 0, stream>>>(h, Wb, z, el, er);
    k_ex<<<(NEDGES * NH + 255) / 256, 256, 0, stream>>>(src, dst, el, er, exbuf);

    k_hist<<<(NEDGES + 255) / 256, 256, 0, stream>>>(dst, cnt);
    kscan1<<<SCAN_BLOCKS, 1024, 0, stream>>>(cnt, inc, bsum);
    kscan2<<<1, 128, 0, stream>>>(bsum, SCAN_BLOCKS);
    kscan3<<<SCAN_BLOCKS, 1024, 0, stream>>>(cnt, inc, bsum, offs, cursor);
    k_scatter<<<(NEDGES + 255) / 256, 256, 0, stream>>>(src, dst, cursor, epair);

    k_agg<<<NNODES / 2, 256, 0, stream>>>(offs, epair, exbuf, z, o, out);
}

// Round 7
// 148.256 us; speedup vs baseline: 1.3750x; 1.3750x over previous
//
#include <hip/hip_runtime.h>
#include <hip/hip_bf16.h>
#include <math.h>

#define NNODES 100000
#define NEDGES 600000
#define IN 128
#define HD 128   // NUM_HEADS * OUT_DIM
#define NH 8
#define NEG_SLOPE 0.2f
#define RG_TOTAL (NNODES / 16)   // 6250 row-groups of 16 (exact)
#define NFRAG 36                 // 4 K-steps * 9 col-tiles
#define CT_ALL 9                 // 8 z col-tiles + 1 [el|er] tile

typedef __attribute__((ext_vector_type(8))) short short8v;
typedef __attribute__((ext_vector_type(4))) float f32x4;

__device__ inline unsigned short f2bf(float f) {
    unsigned u = __float_as_uint(f);
    unsigned r = (u + 0x7fff + ((u >> 16) & 1)) >> 16;
    return (unsigned short)r;
}
__device__ inline float bflo(unsigned v) { return __uint_as_float(v << 16); }
__device__ inline float bfhi(unsigned v) { return __uint_as_float(v & 0xffff0000u); }

// ---------------- pack W (+ fused Wl/Wr logit columns) into MFMA fragment order ----------------
__global__ __launch_bounds__(256) void k_pack(
    const float* __restrict__ W, const float* __restrict__ attn_l, const float* __restrict__ attn_r,
    short8v* __restrict__ Wb)
{
    int t = threadIdx.x;
    for (int slot = t; slot < NFRAG * 64; slot += 256) {
        int f = slot >> 6, lane = slot & 63;
        int ks = f / CT_ALL, ct = f % CT_ALL;
        int k0 = ks * 32 + (lane >> 4) * 8;
        short8v v;
        if (ct < 8) {
            int col = ct * 16 + (lane & 15);
            #pragma unroll
            for (int j = 0; j < 8; ++j) v[j] = (short)f2bf(W[(k0 + j) * HD + col]);
        } else {
            int c = lane & 15;
            const float* av = (c < 8) ? attn_l : attn_r;
            int hh = c & 7;
            #pragma unroll
            for (int j = 0; j < 8; ++j) {
                int k = k0 + j;
                float s = 0.f;
                for (int d = 0; d < 16; ++d) s += W[k * HD + hh * 16 + d] * av[hh * 16 + d];
                v[j] = (short)f2bf(s);
            }
        }
        Wb[slot] = v;
    }
}

// ---------------- MFMA GEMM: z = h@W (bf16 out) + el/er ----------------
__global__ __launch_bounds__(256) void k_gemm_mfma(
    const float* __restrict__ h, const short8v* __restrict__ Wb,
    unsigned short* __restrict__ z, float* __restrict__ el, float* __restrict__ er)
{
    __shared__ short8v Bs[NFRAG * 64];   // 36 KB
    const int tid = threadIdx.x;
    {
        const float4* srcp = (const float4*)Wb;
        float4* dstp = (float4*)Bs;
        for (int i = tid; i < NFRAG * 64; i += 256) dstp[i] = srcp[i];
    }
    __syncthreads();

    const int lane  = tid & 63;
    const int rowIn = lane & 15;
    const int kgrp  = lane >> 4;
    int wid = (blockIdx.x * 256 + tid) >> 6;
    const int nw = gridDim.x * 4;

    for (int rg = wid; rg < RG_TOTAL; rg += nw) {
        const int row0 = rg * 16;
        const float* hp = h + (size_t)(row0 + rowIn) * IN + kgrp * 8;

        short8v afr[4];
        #pragma unroll
        for (int ks = 0; ks < 4; ++ks) {
            float4 a0 = *(const float4*)(hp + ks * 32);
            float4 a1 = *(const float4*)(hp + ks * 32 + 4);
            short8v v;
            v[0] = (short)f2bf(a0.x); v[1] = (short)f2bf(a0.y);
            v[2] = (short)f2bf(a0.z); v[3] = (short)f2bf(a0.w);
            v[4] = (short)f2bf(a1.x); v[5] = (short)f2bf(a1.y);
            v[6] = (short)f2bf(a1.z); v[7] = (short)f2bf(a1.w);
            afr[ks] = v;
        }

        f32x4 acc[CT_ALL];
        #pragma unroll
        for (int ct = 0; ct < CT_ALL; ++ct) acc[ct] = (f32x4){0.f, 0.f, 0.f, 0.f};

        #pragma unroll
        for (int ks = 0; ks < 4; ++ks)
            #pragma unroll
            for (int ct = 0; ct < CT_ALL; ++ct)
                acc[ct] = __builtin_amdgcn_mfma_f32_16x16x32_bf16(
                    afr[ks], Bs[(ks * CT_ALL + ct) * 64 + lane], acc[ct], 0, 0, 0);

        const int rbase = row0 + kgrp * 4;
        #pragma unroll
        for (int ct = 0; ct < 8; ++ct)
            #pragma unroll
            for (int r = 0; r < 4; ++r)
                z[(size_t)(rbase + r) * HD + ct * 16 + rowIn] = f2bf(acc[ct][r]);

        #pragma unroll
        for (int r = 0; r < 4; ++r) {
            float v = acc[8][r];
            int row = rbase + r;
            if (rowIn < 8) el[row * NH + rowIn] = v;
            else           er[row * NH + rowIn - 8] = v;
        }
    }
}

// ---------------- CSR build ----------------
__global__ void k_hist(const int* __restrict__ dst, int* __restrict__ cnt) {
    int e = blockIdx.x * blockDim.x + threadIdx.x;
    if (e >= NEDGES) return;
    atomicAdd(&cnt[dst[e]], 1);
}

__global__ __launch_bounds__(1024) void kscan1(const int* __restrict__ cnt,
                                               int* __restrict__ inc, int* __restrict__ bsum) {
    __shared__ int buf[2][1024];
    int t = threadIdx.x;
    int i = blockIdx.x * 1024 + t;
    int v = (i < NNODES) ? cnt[i] : 0;
    buf[0][t] = v; __syncthreads();
    int cur = 0;
    for (int off = 1; off < 1024; off <<= 1) {
        int nv = buf[cur][t];
        if (t >= off) nv += buf[cur][t - off];
        buf[cur ^ 1][t] = nv; __syncthreads();
        cur ^= 1;
    }
    if (i < NNODES) inc[i] = buf[cur][t];
    if (t == 1023) bsum[blockIdx.x] = buf[cur][1023];
}

__global__ __launch_bounds__(128) void kscan2(int* __restrict__ bsum, int n) {
    __shared__ int buf[2][128];
    int t = threadIdx.x;
    int v = (t < n) ? bsum[t] : 0;
    buf[0][t] = v; __syncthreads();
    int cur = 0;
    for (int off = 1; off < 128; off <<= 1) {
        int nv = buf[cur][t];
        if (t >= off) nv += buf[cur][t - off];
        buf[cur ^ 1][t] = nv; __syncthreads();
        cur ^= 1;
    }
    if (t < n) bsum[t] = buf[cur][t] - v;
}

__global__ __launch_bounds__(1024) void kscan3(const int* __restrict__ cnt, const int* __restrict__ inc,
                                               const int* __restrict__ bsum,
                                               int* __restrict__ offs, int* __restrict__ cursor) {
    int t = threadIdx.x;
    int i = blockIdx.x * 1024 + t;
    if (i < NNODES) {
        int ex = inc[i] - cnt[i] + bsum[blockIdx.x];
        offs[i] = ex;
        cursor[i] = ex;
    }
    if (i == 0) offs[NNODES] = NEDGES;
}

__global__ void k_scatter(const int* __restrict__ src, const int* __restrict__ dst,
                          int* __restrict__ cursor, int* __restrict__ esrc) {
    int e = blockIdx.x * blockDim.x + threadIdx.x;
    if (e >= NEDGES) return;
    int d = dst[e];
    int pos = atomicAdd(&cursor[d], 1);
    esrc[pos] = src[e];
}

// ---------------- aggregate: one wave per node, batched-MLP gather ----------------
// Edge ids for a node are contiguous: grab up to 64 with ONE lane-parallel load,
// then per batch of 8 edges broadcast ids via shfl and issue all 16 loads
// (8x er + 8x z-row) back-to-back -> 16 loads in flight, one wait per batch.
__global__ __launch_bounds__(256) void k_agg(
    const int* __restrict__ offs, const int* __restrict__ esrc,
    const float* __restrict__ el, const float* __restrict__ er,
    const unsigned short* __restrict__ z, const float* __restrict__ o,
    float* __restrict__ out)
{
    const int wid  = (blockIdx.x * blockDim.x + threadIdx.x) >> 6;
    const int lane = threadIdx.x & 63;
    if (wid >= NNODES) return;
    const int d = wid;
    const int p0 = offs[d];
    const int n  = offs[d + 1] - p0;
    const int hh = lane >> 3;
    const float el8 = el[d * NH + hh];

    float srun = 0.f, a0 = 0.f, a1 = 0.f;

    for (int c0 = 0; c0 < n; c0 += 64) {
        const int m = (n - c0 < 64) ? (n - c0) : 64;   // wave-uniform
        int sid = esrc[p0 + c0 + (lane < m ? lane : 0)];

        for (int b = 0; b < m; b += 8) {
            unsigned zb[8]; float erv[8];
            #pragma unroll
            for (int k = 0; k < 8; ++k) {
                int idx = (b + k < m) ? (b + k) : b;     // clamp tail to a live lane
                int s = __shfl(sid, idx, 64);
                erv[k] = er[s * NH + hh];
                zb[k]  = ((const unsigned*)(z + (size_t)s * HD))[lane];
            }
            #pragma unroll
            for (int k = 0; k < 8; ++k) {
                float ev = el8 + erv[k];
                ev = (ev >= 0.f) ? ev : NEG_SLOPE * ev;
                float ex = (b + k < m) ? __expf(ev) : 0.f;   // uniform select
                srun += ex;
                a0 = fmaf(ex, bflo(zb[k]), a0);
                a1 = fmaf(ex, bfhi(zb[k]), a1);
            }
        }
    }

    const size_t base = (size_t)d * HD + 2 * lane;
    float inv = (srun > 0.f) ? 1.f / srun : 0.f;
    float r0 = a0 * inv, r1 = a1 * inv;
    r0 = (r0 > 0.f) ? r0 : expm1f(r0);
    r1 = (r1 > 0.f) ? r1 : expm1f(r1);
    out[base]     = o[base]     + r0;
    out[base + 1] = o[base + 1] + r1;
}

extern "C" void kernel_launch(void* const* d_in, const int* in_sizes, int n_in,
                              void* d_out, int out_size, void* d_ws, size_t ws_size,
                              hipStream_t stream) {
    const float* h      = (const float*)d_in[0];
    const float* o      = (const float*)d_in[1];
    const float* W      = (const float*)d_in[2];
    const float* attn_l = (const float*)d_in[3];
    const float* attn_r = (const float*)d_in[4];
    const int*   src    = (const int*)d_in[5];
    const int*   dst    = (const int*)d_in[6];
    float* out = (float*)d_out;

    char* ws = (char*)d_ws;
    unsigned short* z = (unsigned short*)(ws);         // 25,600,000 B (bf16)
    float* el     = (float*)(ws + 25600000);           //  3,200,000
    float* er     = (float*)(ws + 28800000);           //  3,200,000
    int*   cnt    = (int*)  (ws + 32000000);           //    400,000
    int*   inc    = (int*)  (ws + 32400000);           //    400,000
    int*   offs   = (int*)  (ws + 32800000);           //    400,016
    int*   cursor = (int*)  (ws + 33200016);           //    400,000
    int*   bsum   = (int*)  (ws + 33600016);           //        512
    int*   esrc   = (int*)  (ws + 33600528);           //  2,400,000
    short8v* Wb   = (short8v*)(ws + 36000528);         //     36,864  (end ~36 MB)

    const int SCAN_BLOCKS = (NNODES + 1023) / 1024;    // 98

    hipMemsetAsync(cnt, 0, NNODES * sizeof(int), stream);

    k_pack<<<1, 256, 0, stream>>>(W, attn_l, attn_r, Wb);
    k_gemm_mfma<<<512, 256, 0, stream>>>(h, Wb, z, el, er);

    k_hist<<<(NEDGES + 255) / 256, 256, 0, stream>>>(dst, cnt);
    kscan1<<<SCAN_BLOCKS, 1024, 0, stream>>>(cnt, inc, bsum);
    kscan2<<<1, 128, 0, stream>>>(bsum, SCAN_BLOCKS);
    kscan3<<<SCAN_BLOCKS, 1024, 0, stream>>>(cnt, inc, bsum, offs, cursor);
    k_scatter<<<(NEDGES + 255) / 256, 256, 0, stream>>>(src, dst, cursor, esrc);

    k_agg<<<(NNODES * 64 + 255) / 256, 256, 0, stream>>>(offs, esrc, el, er, z, o, out);
}